// Round 5
// baseline (411.620 us; speedup 1.0000x reference)
//
#include <hip/hip_runtime.h>
#include <math.h>

#define NN 16384
#define IN_DIM 4
#define HID 64
#define OUT_DIM 2
#define BK 256              // K floats per tile (1KB per row per stage)
#define NPAIR 32            // tile-pairs: (kt, kt+32) processed together

typedef __bf16 bf16x8 __attribute__((ext_vector_type(8)));
typedef float  f32x4  __attribute__((ext_vector_type(4)));

__device__ __forceinline__ void gload_lds16(const float* g, void* lds) {
    __builtin_amdgcn_global_load_lds(
        (const __attribute__((address_space(1))) void*)g,
        (__attribute__((address_space(3))) void*)lds, 16, 0, 0);
}

template<int N> __device__ __forceinline__ void waitv() {
    asm volatile("s_waitcnt vmcnt(%0)" :: "n"(N) : "memory");
    __builtin_amdgcn_sched_barrier(0);
}

// ---------------------------------------------------------------------------
// Kernel 1: messages = tanh(x@W1+b1)@W2+b2, stored TRANSPOSED as bf16:
// msgT[h][node]. 64 nodes per block, 256 blocks.
// ---------------------------------------------------------------------------
__global__ __launch_bounds__(256) void k_messages(
    const float* __restrict__ x, const float* __restrict__ W1,
    const float* __restrict__ b1, const float* __restrict__ W2,
    const float* __restrict__ b2, __bf16* __restrict__ msgT)
{
    __shared__ float  xs[64 * 4];
    __shared__ float  h1[64 * 64];
    __shared__ __bf16 mt[64 * 66];

    const int t = threadIdx.x;
    const int node0 = blockIdx.x * 64;
    xs[t] = x[node0 * 4 + t];
    __syncthreads();

    const int h = t & 63, g = t >> 6;
    for (int n = g * 16; n < g * 16 + 16; ++n) {
        float acc = b1[h];
        #pragma unroll
        for (int k = 0; k < 4; ++k) acc += xs[n * 4 + k] * W1[k * 64 + h];
        h1[n * 64 + h] = tanhf(acc);
    }
    __syncthreads();
    for (int n = g * 16; n < g * 16 + 16; ++n) {
        float acc = b2[h];
        #pragma unroll 8
        for (int k = 0; k < 64; ++k) acc += h1[n * 64 + k] * W2[k * 64 + h];
        mt[h * 66 + n] = (__bf16)acc;
    }
    __syncthreads();
    for (int slot = t; slot < 512; slot += 256) {
        const int r = slot >> 3, c = (slot & 7) * 8;
        bf16x8 v;
        #pragma unroll
        for (int j = 0; j < 8; ++j) v[j] = mt[r * 66 + c + j];
        *(bf16x8*)(msgT + (size_t)r * NN + node0 + c) = v;
    }
}

// ---------------------------------------------------------------------------
// Kernel 2: agg = adj @ messages via bf16 MFMA, DRAM-PAGE-PAIRED:
// Each wave (16 rows, autonomous) processes k-tile PAIRS (kt, kt+32).
// Its 32KB stage burst = 16 adjacent rows x cols {c, c+32KB}, issued as
// quads (g,c0)(g,c1)(g+1,c0)(g+1,c1) -> full 1KB-page coverage under the
// 128-PC x 256B-interleave HBM3E mapping. Phase rotation (mod 32) spreads
// the 4-PC windows of concurrent waves over all 128 PCs.
// Both streams accumulate into the same fp32 accs (order-only change).
// LDS: As[buf][wave][stream][16*BK] = 128 KB/block (2 waves).
// ---------------------------------------------------------------------------
__global__ __launch_bounds__(128, 1) void k_agg(
    const float* __restrict__ adj, const __bf16* __restrict__ msgT,
    float* __restrict__ agg)
{
    __shared__ float As[2][2][2][16 * BK];   // [buf][wave][stream] : 128 KB

    const int t = threadIdx.x;
    const int wave = t >> 6, lane = t & 63;
    const int m0 = blockIdx.x * 32 + wave * 16;
    const int r15 = lane & 15;
    const int kg  = lane >> 4;
    const int phase = (blockIdx.x * 2 + wave) & (NPAIR - 1);

    const float*  arow  = adj  + (size_t)m0 * NN;
    const __bf16* bbase = msgT + (size_t)r15 * NN + kg * 8;

    f32x4 acc0 = {}, acc1 = {}, acc2 = {}, acc3 = {};
    bf16x8 bc0, bc1, bc2, bc3, bd0, bd1, bd2, bd3;
    bf16x8 bn0, bn1, bn2, bn3, bn4, bn5, bn6, bn7;

    // ---- prologue: stage tile-pair 'phase' as 8 page-quads ----
    {
        const size_t c0 = (size_t)phase * BK;        // floats
        const size_t c1 = c0 + NPAIR * BK;           // +32 tiles = +32KB bytes
        float* d0 = &As[0][wave][0][0];
        float* d1 = &As[0][wave][1][0];
        #pragma unroll
        for (int gp = 0; gp < 8; ++gp) {
            const int g = gp * 2;
            gload_lds16(arow + (size_t)g * NN + c0 + ((lane ^ g) << 2), d0 + g * BK);
            gload_lds16(arow + (size_t)g * NN + c1 + ((lane ^ g) << 2), d1 + g * BK);
            gload_lds16(arow + (size_t)(g + 1) * NN + c0 + ((lane ^ (g + 1)) << 2), d0 + (g + 1) * BK);
            gload_lds16(arow + (size_t)(g + 1) * NN + c1 + ((lane ^ (g + 1)) << 2), d1 + (g + 1) * BK);
        }
        const __bf16* bp0 = bbase + (size_t)phase * BK;
        const __bf16* bp1 = bp0 + (size_t)NPAIR * BK;
        bc0 = *(const bf16x8*)(bp0);
        bc1 = *(const bf16x8*)(bp0 + 16 * (size_t)NN);
        bc2 = *(const bf16x8*)(bp0 + 32 * (size_t)NN);
        bc3 = *(const bf16x8*)(bp0 + 48 * (size_t)NN);
        bd0 = *(const bf16x8*)(bp1);
        bd1 = *(const bf16x8*)(bp1 + 16 * (size_t)NN);
        bd2 = *(const bf16x8*)(bp1 + 32 * (size_t)NN);
        bd3 = *(const bf16x8*)(bp1 + 48 * (size_t)NN);
    }

#define KSTEP(KT, KK, GATE, DOSTAGE, DOBN)                                         \
    {                                                                              \
        if (DOBN) {                                                                \
            const int nkt = ((KK) == 7) ? (KT) + 1 : (KT);                         \
            const int nkk = ((KK) + 1) & 7;                                        \
            const int npt = (nkt + phase) & (NPAIR - 1);                           \
            const __bf16* bp0 = bbase + (size_t)npt * BK + nkk * 32;               \
            const __bf16* bp1 = bp0 + (size_t)NPAIR * BK;                          \
            bn0 = *(const bf16x8*)(bp0);                                           \
            bn1 = *(const bf16x8*)(bp0 + 16 * (size_t)NN);                         \
            bn2 = *(const bf16x8*)(bp0 + 32 * (size_t)NN);                         \
            bn3 = *(const bf16x8*)(bp0 + 48 * (size_t)NN);                         \
            bn4 = *(const bf16x8*)(bp1);                                           \
            bn5 = *(const bf16x8*)(bp1 + 16 * (size_t)NN);                         \
            bn6 = *(const bf16x8*)(bp1 + 32 * (size_t)NN);                         \
            bn7 = *(const bf16x8*)(bp1 + 48 * (size_t)NN);                         \
        }                                                                          \
        if (GATE) waitv<8>();                                                      \
        const float* A0 = &As[(KT) & 1][wave][0][0] + r15 * BK;                    \
        const float* A1 = &As[(KT) & 1][wave][1][0] + r15 * BK;                    \
        f32x4 alo0 = *(const f32x4*)(A0 + ((((KK) * 8 + kg * 2 + 0) ^ r15) << 2)); \
        f32x4 ahi0 = *(const f32x4*)(A0 + ((((KK) * 8 + kg * 2 + 1) ^ r15) << 2)); \
        f32x4 alo1 = *(const f32x4*)(A1 + ((((KK) * 8 + kg * 2 + 0) ^ r15) << 2)); \
        f32x4 ahi1 = *(const f32x4*)(A1 + ((((KK) * 8 + kg * 2 + 1) ^ r15) << 2)); \
        bf16x8 af0, af1;                                                           \
        af0[0] = (__bf16)alo0[0]; af0[1] = (__bf16)alo0[1];                        \
        af0[2] = (__bf16)alo0[2]; af0[3] = (__bf16)alo0[3];                        \
        af0[4] = (__bf16)ahi0[0]; af0[5] = (__bf16)ahi0[1];                        \
        af0[6] = (__bf16)ahi0[2]; af0[7] = (__bf16)ahi0[3];                        \
        af1[0] = (__bf16)alo1[0]; af1[1] = (__bf16)alo1[1];                        \
        af1[2] = (__bf16)alo1[2]; af1[3] = (__bf16)alo1[3];                        \
        af1[4] = (__bf16)ahi1[0]; af1[5] = (__bf16)ahi1[1];                        \
        af1[6] = (__bf16)ahi1[2]; af1[7] = (__bf16)ahi1[3];                        \
        acc0 = __builtin_amdgcn_mfma_f32_16x16x32_bf16(af0, bc0, acc0, 0, 0, 0);   \
        acc1 = __builtin_amdgcn_mfma_f32_16x16x32_bf16(af0, bc1, acc1, 0, 0, 0);   \
        acc2 = __builtin_amdgcn_mfma_f32_16x16x32_bf16(af0, bc2, acc2, 0, 0, 0);   \
        acc3 = __builtin_amdgcn_mfma_f32_16x16x32_bf16(af0, bc3, acc3, 0, 0, 0);   \
        acc0 = __builtin_amdgcn_mfma_f32_16x16x32_bf16(af1, bd0, acc0, 0, 0, 0);   \
        acc1 = __builtin_amdgcn_mfma_f32_16x16x32_bf16(af1, bd1, acc1, 0, 0, 0);   \
        acc2 = __builtin_amdgcn_mfma_f32_16x16x32_bf16(af1, bd2, acc2, 0, 0, 0);   \
        acc3 = __builtin_amdgcn_mfma_f32_16x16x32_bf16(af1, bd3, acc3, 0, 0, 0);   \
        if (DOSTAGE) {                                                             \
            const size_t sc0 = (size_t)(((KT) + 1 + phase) & (NPAIR - 1)) * BK;    \
            const size_t sc1 = sc0 + NPAIR * BK;                                   \
            float* d0 = &As[((KT) + 1) & 1][wave][0][0];                           \
            float* d1 = &As[((KT) + 1) & 1][wave][1][0];                           \
            const int g = (KK) * 2;                                                \
            gload_lds16(arow + (size_t)g * NN + sc0 + ((lane ^ g) << 2), d0 + g * BK); \
            gload_lds16(arow + (size_t)g * NN + sc1 + ((lane ^ g) << 2), d1 + g * BK); \
            gload_lds16(arow + (size_t)(g + 1) * NN + sc0 + ((lane ^ (g + 1)) << 2), d0 + (g + 1) * BK); \
            gload_lds16(arow + (size_t)(g + 1) * NN + sc1 + ((lane ^ (g + 1)) << 2), d1 + (g + 1) * BK); \
        }                                                                          \
        bc0 = bn0; bc1 = bn1; bc2 = bn2; bc3 = bn3;                                \
        bd0 = bn4; bd1 = bn5; bd2 = bn6; bd3 = bn7;                                \
        __builtin_amdgcn_sched_barrier(0);                                         \
    }

    // ---- iter 0 ----
    KSTEP(0, 0, 1, 1, 1);
    #pragma unroll
    for (int kk = 1; kk < 8; ++kk) KSTEP(0, kk, 0, 1, 1);

    // ---- steady state ----
    for (int kt = 1; kt < NPAIR - 1; ++kt) {
        KSTEP(kt, 0, 1, 1, 1);
        #pragma unroll
        for (int kk = 1; kk < 8; ++kk) KSTEP(kt, kk, 0, 1, 1);
    }

    // ---- last tile-pair: no staging; stop B-prefetch at the end ----
    KSTEP((NPAIR - 1), 0, 1, 0, 1);
    #pragma unroll
    for (int kk = 1; kk < 8; ++kk) KSTEP((NPAIR - 1), kk, 0, 0, (kk != 7));
#undef KSTEP

    // ---- epilogue: write agg. D lane l: col=l&15, row=4*(l>>4)+j ----
    const int rb = m0 + kg * 4;
    f32x4 accs[4] = {acc0, acc1, acc2, acc3};
    #pragma unroll
    for (int tt = 0; tt < 4; ++tt) {
        #pragma unroll
        for (int j = 0; j < 4; ++j) {
            agg[(size_t)(rb + j) * HID + tt * 16 + r15] = accs[tt][j];
        }
    }
}

// ---------------------------------------------------------------------------
// Kernel 3: combined=[x,agg]; out = tanh(tanh(combined@U1+c1)@U2+c2)@Wo + bo.
// 64 nodes/block, 256 blocks.
// ---------------------------------------------------------------------------
__global__ __launch_bounds__(256) void k_update(
    const float* __restrict__ x, const float* __restrict__ agg,
    const float* __restrict__ U1, const float* __restrict__ c1,
    const float* __restrict__ U2, const float* __restrict__ c2,
    const float* __restrict__ Wo, const float* __restrict__ bo,
    float* __restrict__ out)
{
    __shared__ float comb[64 * 73];
    __shared__ float h1s[64 * 66];

    const int t = threadIdx.x, h = t & 63, g = t >> 6;
    const int node0 = blockIdx.x * 64;

    comb[(t >> 2) * 73 + (t & 3)] = x[node0 * 4 + t];
    for (int n = g * 16; n < g * 16 + 16; ++n) {
        comb[n * 73 + 4 + h] = agg[(size_t)(node0 + n) * HID + h];
    }
    __syncthreads();
    for (int n = g * 16; n < g * 16 + 16; ++n) {
        float acc = c1[h];
        #pragma unroll 4
        for (int k = 0; k < 68; ++k) acc += comb[n * 73 + k] * U1[k * 64 + h];
        h1s[n * 66 + h] = tanhf(acc);
    }
    __syncthreads();
    for (int n = g * 16; n < g * 16 + 16; ++n) {
        float acc = c2[h];
        #pragma unroll 8
        for (int k = 0; k < 64; ++k) acc += h1s[n * 66 + k] * U2[k * 64 + h];
        comb[n * 73 + h] = tanhf(acc);
    }
    __syncthreads();
    if (t < 128) {
        const int n = t >> 1, o = t & 1;
        float acc = bo[o];
        #pragma unroll 8
        for (int k = 0; k < 64; ++k) acc += comb[n * 73 + k] * Wo[k * 2 + o];
        out[(size_t)(node0 + n) * 2 + o] = acc;
    }
}

// ---------------------------------------------------------------------------
extern "C" void kernel_launch(void* const* d_in, const int* in_sizes, int n_in,
                              void* d_out, int out_size, void* d_ws, size_t ws_size,
                              hipStream_t stream)
{
    const float* x   = (const float*)d_in[0];
    const float* adj = (const float*)d_in[1];
    const float* W1  = (const float*)d_in[2];
    const float* b1  = (const float*)d_in[3];
    const float* W2  = (const float*)d_in[4];
    const float* b2  = (const float*)d_in[5];
    const float* U1  = (const float*)d_in[6];
    const float* c1  = (const float*)d_in[7];
    const float* U2  = (const float*)d_in[8];
    const float* c2  = (const float*)d_in[9];
    const float* Wo  = (const float*)d_in[10];
    const float* bo  = (const float*)d_in[11];
    float* out = (float*)d_out;

    // ws layout: [msgT: 64*16384 bf16 = 2 MB][agg: 16384*64 f32 = 4 MB]
    __bf16* msgT = (__bf16*)d_ws;
    float*  agg  = (float*)((char*)d_ws + (size_t)HID * NN * sizeof(__bf16));

    k_messages<<<NN / 64, 256, 0, stream>>>(x, W1, b1, W2, b2, msgT);
    k_agg<<<NN / 32, 128, 0, stream>>>(adj, msgT, agg);
    k_update<<<NN / 64, 256, 0, stream>>>(x, agg, U1, c1, U2, c2, Wo, bo, out);
}